// Round 1
// baseline (132.966 us; speedup 1.0000x reference)
//
#include <hip/hip_runtime.h>
#include <math.h>

#define B_ 64
#define P_ 24564
#define G_ 48

// Workspace layout (total ~3.75 MB), everything fully overwritten every call (no memset):
//   [0]        unsigned long long bkey[B_][G_][NCH]   per-(b,g,chunk) best-prior keys
//   [589824]   unsigned short mrec[B_*PAD_P]          i1|i2<<6|pos<<12
//   [3735552]  float        pl[NBLK]                  per-block loss partials
//   [3741696]  unsigned int pn[NBLK]                  per-block npos partials
//   [3747840]  double       corrl[B_]                 per-image corrections
//   [3748352]  unsigned int corrn[B_]
constexpr int CH    = 1024;
constexpr int NCH   = 24;               // 24*1024 = 24576 >= P_
constexpr int PAD_P = NCH * CH;
constexpr int PPT   = 8;                // priors per thread (was 4) — halves per-g overhead
constexpr int NTHR  = 128;              // match block size (was 256); CH unchanged => same key semantics
constexpr int NBLK  = NCH * B_;         // 1536
constexpr int ROW   = 68;               // kgrid row in u32 (64 entries + pad, keeps 16B align)

__device__ __forceinline__ float frcp(float x) { return __builtin_amdgcn_rcpf(x); }

// Smooth-ln repulsion term; identical in match (default) and fix (correction) so terms cancel.
__device__ __forceinline__ float loss_term(float4 pr, float4 l, float4 gb, float ga) {
    float cx = pr.x + l.x * 0.1f * pr.z;
    float cy = pr.y + l.y * 0.1f * pr.w;
    float w  = pr.z * expf(l.z * 0.2f);
    float h  = pr.w * expf(l.w * 0.2f);
    float dx1 = cx - w * 0.5f, dy1 = cy - h * 0.5f;
    float dx2 = cx + w * 0.5f, dy2 = cy + h * 0.5f;
    float ix1 = fmaxf(gb.x, dx1), iy1 = fmaxf(gb.y, dy1);
    float ix2 = fminf(gb.z, dx2), iy2 = fminf(gb.w, dy2);
    float iw = fmaxf(ix2 - ix1, 0.0f), ih = fmaxf(iy2 - iy1, 0.0f);
    float iogv = (iw * ih) * frcp(ga + 1e-7f);
    float r = 0.0f;
    if (iogv < 0.95f) {
        if (iogv < 0.5f)
            r = -logf(1.0f - iogv + 1e-7f);
        else
            r = (iogv - 0.5f) * 2.0f + 0.69314718055994531f;  // -ln(0.5)
    }
    return r;
}

// ---------------- K1: fused — top-2 per prior, per-gt block argmax, default loss ------------
// 128 threads x 8 priors/thread over the same CH=1024 chunk: identical tie-break semantics,
// half the per-g LDS/shuffle/loop overhead per pair, kgrid rows shrink 128 -> 64 entries.
__global__ __launch_bounds__(NTHR, 3) void match_kernel(
    const float* __restrict__ pred_loc, const float* __restrict__ priors,
    const float* __restrict__ gt, unsigned long long* __restrict__ bkey,
    unsigned short* __restrict__ mrec, float* __restrict__ pl, unsigned int* __restrict__ pn) {
    const int b    = blockIdx.y;
    const int base = blockIdx.x * CH;
    const int tid  = threadIdx.x;

    __shared__ float4 sbox[G_];
    __shared__ float  sga[G_];
    __shared__ unsigned int kgrid[G_ * ROW];   // pair-reduced per-gt candidate keys (64/gt)
    __shared__ unsigned int pmax[G_][2];
    __shared__ float rs[2];
    __shared__ unsigned int rn[2];

    if (tid < G_) {
        const float* q = gt + ((size_t)b * G_ + tid) * 5;
        float x1 = q[0], y1 = q[1], x2 = q[2], y2 = q[3];
        sbox[tid] = make_float4(x1, y1, x2, y2);
        sga[tid]  = (x2 - x1) * (y2 - y1);
    }
    __syncthreads();

    float px1[PPT], py1[PPT], px2[PPT], py2[PPT], pa[PPT];
    unsigned int tb[PPT];  // 1023 - local_p (per-gt tie-break: lower p wins)
#pragma unroll
    for (int j = 0; j < PPT; j++) {
        int lp = tid + NTHR * j;
        int pc = min(base + lp, P_ - 1);  // clamped OOB dup loses tie-break to the real one
        float4 pr = ((const float4*)priors)[pc];
        float hx = pr.z * 0.5f, hy = pr.w * 0.5f;
        px1[j] = pr.x - hx; py1[j] = pr.y - hy;
        px2[j] = pr.x + hx; py2[j] = pr.y + hy;
        pa[j] = (px2[j] - px1[j]) * (py2[j] - py1[j]);
        tb[j] = (unsigned)(1023 - lp);
    }

    unsigned int k1[PPT], k2[PPT];  // packed top-2 of r=inter/(ga+pa): (r&~0x3F)|(63-g)
#pragma unroll
    for (int j = 0; j < PPT; j++) { k1[j] = 0u; k2[j] = 0u; }

#pragma unroll 4
    for (int g = 0; g < G_; g++) {
        float4 gb = sbox[g];
        float  ga = sga[g];
        unsigned int gmax = 0u;
#pragma unroll
        for (int j = 0; j < PPT; j++) {
            float ix1 = fmaxf(gb.x, px1[j]), iy1 = fmaxf(gb.y, py1[j]);
            float ix2 = fminf(gb.z, px2[j]), iy2 = fminf(gb.w, py2[j]);
            float iw = fmaxf(ix2 - ix1, 0.0f), ih = fmaxf(iy2 - iy1, 0.0f);
            float inter = iw * ih;
            // r = inter/(ga+pa) is a monotone transform of IoU=inter/(ga+pa-inter)
            float r = inter * frcp(ga + pa[j]);
            unsigned int vb = __float_as_uint(r);
            unsigned int pk = (vb & 0xFFFFFFC0u) | (unsigned)(63 - g);
            // top-2 update: new k2 = median(k1, k2, pk) under invariant k1 >= k2 (1 op vs min+max)
            unsigned int nk2;
            asm("v_med3_u32 %0, %1, %2, %3" : "=v"(nk2) : "v"(k1[j]), "v"(k2[j]), "v"(pk));
            k2[j] = nk2;
            k1[j] = max(k1[j], pk);
            unsigned int gk = (vb & 0xFFFFFC00u) | tb[j];
            gmax = max(gmax, gk);
        }
        // pair-reduce across adjacent lanes via xor-1 swizzle, even lanes store -> 64-entry rows
        unsigned int o = (unsigned int)__builtin_amdgcn_ds_swizzle((int)gmax, 0x041F);
        if ((tid & 1) == 0) kgrid[g * ROW + (tid >> 1)] = max(gmax, o);
    }

    // per-prior epilogue: default contribution assumes NO override (bi=i1 -> rep=i2)
    float contrib = 0.0f;
    unsigned int np = 0;
#pragma unroll
    for (int j = 0; j < PPT; j++) {
        int p = base + tid + NTHR * j;
        unsigned int i1 = 63u - (k1[j] & 63u);
        unsigned int i2 = 63u - (k2[j] & 63u);
        // r >= 1/3  <=>  IoU >= 0.5 ; truncated-key threshold (bits(1/3f) & ~0x3F)
        unsigned int pos = (k1[j] >= 0x3EAAAA80u) ? 1u : 0u;
        mrec[(size_t)b * PAD_P + p] = (unsigned short)(i1 | (i2 << 6) | (pos << 12));
        if (p < P_ && pos) {
            float4 pr = ((const float4*)priors)[p];               // L1-hot reload
            float4 l  = ((const float4*)pred_loc)[(size_t)b * P_ + p];
            contrib += loss_term(pr, l, sbox[i2], sga[i2]);
            np++;
        }
    }

    const int lane = tid & 63, wv = tid >> 6;
    for (int off = 32; off; off >>= 1) {
        contrib += __shfl_down(contrib, off, 64);
        np      += __shfl_down(np, off, 64);
    }
    if (lane == 0) { rs[wv] = contrib; rn[wv] = np; }
    __syncthreads();  // kgrid + rs/rn visible

    // per-gt argmax within block: 2 readers per gt scan 32 entries each
    if (tid < 96) {
        int g = tid >> 1, q = tid & 1;
        const uint4* row = (const uint4*)&kgrid[g * ROW + q * 32];
        unsigned int m = 0u;
#pragma unroll
        for (int i = 0; i < 8; i++) {
            uint4 v = row[i];
            m = max(max(m, v.x), max(v.y, max(v.z, v.w)));
        }
        pmax[g][q] = m;
    } else if (tid == 127) {
        pl[b * NCH + blockIdx.x] = rs[0] + rs[1];
        pn[b * NCH + blockIdx.x] = rn[0] + rn[1];
    }
    __syncthreads();

    if (tid < G_) {
        unsigned int w = max(pmax[tid][0], pmax[tid][1]);
        int p = base + 1023 - (int)(w & 0x3FFu);
        p = min(p, P_ - 1);  // defensive; unreachable via tie-break
        float4 pr = ((const float4*)priors)[p];
        float hx = pr.z * 0.5f, hy = pr.w * 0.5f;
        float qx1 = pr.x - hx, qy1 = pr.y - hy, qx2 = pr.x + hx, qy2 = pr.y + hy;
        float pae = (qx2 - qx1) * (qy2 - qy1);
        float4 gb = sbox[tid];
        float ix1 = fmaxf(gb.x, qx1), iy1 = fmaxf(gb.y, qy1);
        float ix2 = fminf(gb.z, qx2), iy2 = fminf(gb.w, qy2);
        float iw = fmaxf(ix2 - ix1, 0.0f), ih = fmaxf(iy2 - iy1, 0.0f);
        float inter = iw * ih;
        // exact (bit-stable across blocks) IoU-form key for cross-block comparison
        float v = inter * frcp(sga[tid] + pae - inter);
        // layout [b][g][chunk]: fix kernel reads each (b,g)'s 24 keys contiguously
        bkey[((size_t)b * G_ + tid) * NCH + blockIdx.x] =
            ((unsigned long long)__float_as_uint(v) << 32) |
            (unsigned long long)(0xFFFFFFFFu - (unsigned)p);
    }
}

// ---------------- K2: per-image bkey reduce + override corrections (64 blocks) --------------
__global__ __launch_bounds__(64) void fix_kernel(
    const float* __restrict__ pred_loc, const float* __restrict__ priors,
    const float* __restrict__ gt, const unsigned long long* __restrict__ bkey,
    const unsigned short* __restrict__ mrec,
    double* __restrict__ corrl, unsigned int* __restrict__ corrn) {
    const int b = blockIdx.x, g = threadIdx.x;
    __shared__ int sp[G_];
    int p = -1;
    if (g < G_) {
        const unsigned long long* row = bkey + ((size_t)b * G_ + g) * NCH;
        unsigned long long m = 0ull;
#pragma unroll
        for (int c = 0; c < NCH; c++) m = max(m, row[c]);
        p = (int)(0xFFFFFFFFu - (unsigned)(m & 0xFFFFFFFFull));
        sp[g] = p;
    }
    __syncthreads();

    double delta = 0.0;
    unsigned int dn = 0;
    if (g < G_) {
        // last-write-wins: g is alive iff no larger g' shares the same best prior
        bool alive = true;
        for (int d = g + 1; d < G_; d++)
            if (sp[d] == p) alive = false;
        if (alive) {
            unsigned int m = mrec[(size_t)b * PAD_P + p];
            int i1 = (int)(m & 63u), i2 = (int)((m >> 6) & 63u);
            bool pos0 = (m >> 12) & 1u;
            int ri = (g == i1) ? i2 : i1;   // override bi=g -> rep flips to i1 unless g==i1
            float4 pr = ((const float4*)priors)[p];
            float4 l  = ((const float4*)pred_loc)[(size_t)b * P_ + p];
            const float* qr = gt + ((size_t)b * G_ + ri) * 5;
            float4 gbr = make_float4(qr[0], qr[1], qr[2], qr[3]);
            float gar = (qr[2] - qr[0]) * (qr[3] - qr[1]);
            float cnew = loss_term(pr, l, gbr, gar);
            float cold = 0.0f;
            if (pos0) {
                const float* q2 = gt + ((size_t)b * G_ + i2) * 5;
                float4 gb2 = make_float4(q2[0], q2[1], q2[2], q2[3]);
                float ga2 = (q2[2] - q2[0]) * (q2[3] - q2[1]);
                cold = loss_term(pr, l, gb2, ga2);   // cancels match's default term
            } else {
                dn = 1;                               // prior newly positive
            }
            delta = (double)cnew - (double)cold;
        }
    }
    for (int off = 32; off; off >>= 1) {
        delta += __shfl_down(delta, off, 64);
        dn    += __shfl_down(dn, off, 64);
    }
    if (g == 0) { corrl[b] = delta; corrn[b] = dn; }
}

// ---------------- K3: final reduction --------------------------------------------------------
__global__ __launch_bounds__(256) void final_kernel(
    const float* __restrict__ pl, const unsigned int* __restrict__ pn,
    const double* __restrict__ corrl, const unsigned int* __restrict__ corrn,
    float* __restrict__ out) {
    const int tid = threadIdx.x;
    double acc = 0.0;
    unsigned int n = 0;
    for (int i = tid; i < NBLK; i += 256) { acc += (double)pl[i]; n += pn[i]; }
    if (tid < B_) { acc += corrl[tid]; n += corrn[tid]; }
    for (int off = 32; off; off >>= 1) {
        acc += __shfl_down(acc, off, 64);
        n   += __shfl_down(n, off, 64);
    }
    __shared__ double ds[4];
    __shared__ unsigned int dns[4];
    const int lane = tid & 63, wv = tid >> 6;
    if (lane == 0) { ds[wv] = acc; dns[wv] = n; }
    __syncthreads();
    if (tid == 0) {
        double s = ds[0] + ds[1] + ds[2] + ds[3];
        unsigned int nn = dns[0] + dns[1] + dns[2] + dns[3];
        out[0] = (float)(s / (double)nn);
    }
}

extern "C" void kernel_launch(void* const* d_in, const int* in_sizes, int n_in,
                              void* d_out, int out_size, void* d_ws, size_t ws_size,
                              hipStream_t stream) {
    const float* pred_loc = (const float*)d_in[0];  // [B,P,4]
    const float* priors   = (const float*)d_in[1];  // [P,4]
    const float* gt       = (const float*)d_in[2];  // [B,G,5]
    float* out = (float*)d_out;

    char* ws = (char*)d_ws;
    unsigned long long* bkey = (unsigned long long*)ws;                   // 589824 B
    unsigned short* mrec = (unsigned short*)(ws + 589824);                // 3145728 B
    float*        pl    = (float*)(ws + 3735552);                         // 6144 B
    unsigned int* pn    = (unsigned int*)(ws + 3741696);                  // 6144 B
    double*       corrl = (double*)(ws + 3747840);                        // 512 B
    unsigned int* corrn = (unsigned int*)(ws + 3748352);                  // 256 B

    dim3 g1(NCH, B_);
    match_kernel<<<g1, NTHR, 0, stream>>>(pred_loc, priors, gt, bkey, mrec, pl, pn);

    fix_kernel<<<B_, 64, 0, stream>>>(pred_loc, priors, gt, bkey, mrec, corrl, corrn);

    final_kernel<<<1, 256, 0, stream>>>(pl, pn, corrl, corrn, out);
}

// Round 2
// 120.556 us; speedup vs baseline: 1.1029x; 1.1029x over previous
//
#include <hip/hip_runtime.h>
#include <math.h>

#define B_ 64
#define P_ 24564
#define G_ 48

// Workspace layout (total ~3.75 MB), everything fully overwritten every call (no memset):
//   [0]        unsigned long long bkey[B_][G_][NCH]   per-(b,g,chunk) best-prior keys
//   [589824]   unsigned short mrec[B_*PAD_P]          i1|i2<<6|pos<<12
//   [3735552]  float        pl[NBLK]                  per-block loss partials
//   [3741696]  unsigned int pn[NBLK]                  per-block npos partials
//   [3747840]  double       corrl[B_]                 per-image corrections
//   [3748352]  unsigned int corrn[B_]
constexpr int CH    = 1024;
constexpr int NCH   = 24;               // 24*1024 = 24576 >= P_
constexpr int PAD_P = NCH * CH;
constexpr int PPT   = 4;
constexpr int NBLK  = NCH * B_;         // 1536
constexpr int ROW   = 132;              // kgrid row in u32 (128 entries + pad)

__device__ __forceinline__ float frcp(float x) { return __builtin_amdgcn_rcpf(x); }

// Smooth-ln repulsion term; identical in match (default) and fix (correction) so terms cancel.
__device__ __forceinline__ float loss_term(float4 pr, float4 l, float4 gb, float ga) {
    float cx = pr.x + l.x * 0.1f * pr.z;
    float cy = pr.y + l.y * 0.1f * pr.w;
    float w  = pr.z * expf(l.z * 0.2f);
    float h  = pr.w * expf(l.w * 0.2f);
    float dx1 = cx - w * 0.5f, dy1 = cy - h * 0.5f;
    float dx2 = cx + w * 0.5f, dy2 = cy + h * 0.5f;
    float ix1 = fmaxf(gb.x, dx1), iy1 = fmaxf(gb.y, dy1);
    float ix2 = fminf(gb.z, dx2), iy2 = fminf(gb.w, dy2);
    float iw = fmaxf(ix2 - ix1, 0.0f), ih = fmaxf(iy2 - iy1, 0.0f);
    float iogv = (iw * ih) * frcp(ga + 1e-7f);
    float r = 0.0f;
    if (iogv < 0.95f) {
        if (iogv < 0.5f)
            r = -logf(1.0f - iogv + 1e-7f);
        else
            r = (iogv - 0.5f) * 2.0f + 0.69314718055994531f;  // -ln(0.5)
    }
    return r;
}

// ---------------- K1: fused — top-2 per prior, per-gt block argmax, default loss ------------
// __launch_bounds__(256, 4): cap at 4 waves/EU -> up to 128 VGPRs, so the per-thread live set
// (prior geometry for 4 priors + top-2 keys + gt box) stays register-resident across the g-loop
// instead of being rematerialized (VGPR=44 build measured ~44 issue slots/pair vs ~17 ideal).
__global__ __launch_bounds__(256, 4) void match_kernel(
    const float* __restrict__ pred_loc, const float* __restrict__ priors,
    const float* __restrict__ gt, unsigned long long* __restrict__ bkey,
    unsigned short* __restrict__ mrec, float* __restrict__ pl, unsigned int* __restrict__ pn) {
    const int b    = blockIdx.y;
    const int base = blockIdx.x * CH;
    const int tid  = threadIdx.x;

    __shared__ float4 sbox[G_];
    __shared__ float  sga[G_];
    __shared__ unsigned int kgrid[G_ * ROW];   // pair-reduced per-gt candidate keys
    __shared__ unsigned int pmax[G_][4];
    __shared__ float rs[4];
    __shared__ unsigned int rn[4];

    if (tid < G_) {
        const float* q = gt + ((size_t)b * G_ + tid) * 5;
        float x1 = q[0], y1 = q[1], x2 = q[2], y2 = q[3];
        sbox[tid] = make_float4(x1, y1, x2, y2);
        sga[tid]  = (x2 - x1) * (y2 - y1);
    }
    __syncthreads();

    float px1[PPT], py1[PPT], px2[PPT], py2[PPT], pa[PPT];
    unsigned int tb[PPT];  // 1023 - local_p (per-gt tie-break: lower p wins)
#pragma unroll
    for (int j = 0; j < PPT; j++) {
        int lp = tid + 256 * j;
        int pc = min(base + lp, P_ - 1);  // clamped OOB dup loses tie-break to the real one
        float4 pr = ((const float4*)priors)[pc];
        float hx = pr.z * 0.5f, hy = pr.w * 0.5f;
        px1[j] = pr.x - hx; py1[j] = pr.y - hy;
        px2[j] = pr.x + hx; py2[j] = pr.y + hy;
        pa[j] = (px2[j] - px1[j]) * (py2[j] - py1[j]);
        tb[j] = (unsigned)(1023 - lp);
    }

    unsigned int k1[PPT], k2[PPT];  // packed top-2 of r=inter/(ga+pa): (r&~0x3F)|(63-g)
#pragma unroll
    for (int j = 0; j < PPT; j++) { k1[j] = 0u; k2[j] = 0u; }

#pragma unroll 8
    for (int g = 0; g < G_; g++) {
        float4 gb = sbox[g];
        float  ga = sga[g];
        unsigned int gmax = 0u;
#pragma unroll
        for (int j = 0; j < PPT; j++) {
            float ix1 = fmaxf(gb.x, px1[j]), iy1 = fmaxf(gb.y, py1[j]);
            float ix2 = fminf(gb.z, px2[j]), iy2 = fminf(gb.w, py2[j]);
            float iw = fmaxf(ix2 - ix1, 0.0f), ih = fmaxf(iy2 - iy1, 0.0f);
            float inter = iw * ih;
            // r = inter/(ga+pa) is a monotone transform of IoU=inter/(ga+pa-inter)
            float r = inter * frcp(ga + pa[j]);
            unsigned int vb = __float_as_uint(r);
            unsigned int pk = (vb & 0xFFFFFFC0u) | (unsigned)(63 - g);
            // top-2 update: new k2 = median(k1, k2, pk) under invariant k1 >= k2 (1 op vs min+max)
            unsigned int nk2;
            asm("v_med3_u32 %0, %1, %2, %3" : "=v"(nk2) : "v"(k1[j]), "v"(k2[j]), "v"(pk));
            k2[j] = nk2;
            k1[j] = max(k1[j], pk);
            unsigned int gk = (vb & 0xFFFFFC00u) | tb[j];
            gmax = max(gmax, gk);
        }
        // pair-reduce across adjacent lanes via xor-1 swizzle, even lanes store -> 128-entry rows
        unsigned int o = (unsigned int)__builtin_amdgcn_ds_swizzle((int)gmax, 0x041F);
        if ((tid & 1) == 0) kgrid[g * ROW + (tid >> 1)] = max(gmax, o);
    }

    // per-prior epilogue: default contribution assumes NO override (bi=i1 -> rep=i2)
    float contrib = 0.0f;
    unsigned int np = 0;
#pragma unroll
    for (int j = 0; j < PPT; j++) {
        int p = base + tid + 256 * j;
        unsigned int i1 = 63u - (k1[j] & 63u);
        unsigned int i2 = 63u - (k2[j] & 63u);
        // r >= 1/3  <=>  IoU >= 0.5 ; truncated-key threshold (bits(1/3f) & ~0x3F)
        unsigned int pos = (k1[j] >= 0x3EAAAA80u) ? 1u : 0u;
        mrec[(size_t)b * PAD_P + base + tid + 256 * j] =
            (unsigned short)(i1 | (i2 << 6) | (pos << 12));
        if (p < P_ && pos) {
            float4 pr = ((const float4*)priors)[p];               // L1-hot reload
            float4 l  = ((const float4*)pred_loc)[(size_t)b * P_ + p];
            contrib += loss_term(pr, l, sbox[i2], sga[i2]);
            np++;
        }
    }

    const int lane = tid & 63, wv = tid >> 6;
    for (int off = 32; off; off >>= 1) {
        contrib += __shfl_down(contrib, off, 64);
        np      += __shfl_down(np, off, 64);
    }
    if (lane == 0) { rs[wv] = contrib; rn[wv] = np; }
    __syncthreads();  // kgrid + rs/rn visible

    // per-gt argmax within block: 4 readers per gt scan 32 entries each
    if (tid < 192) {
        int g = tid >> 2, qq = tid & 3;
        const uint4* row = (const uint4*)&kgrid[g * ROW + qq * 32];
        unsigned int m = 0u;
#pragma unroll
        for (int i = 0; i < 8; i++) {
            uint4 v = row[i];
            m = max(max(m, v.x), max(v.y, max(v.z, v.w)));
        }
        pmax[g][qq] = m;
    }
    __syncthreads();

    if (tid < G_) {
        unsigned int w = max(max(pmax[tid][0], pmax[tid][1]),
                             max(pmax[tid][2], pmax[tid][3]));
        int p = base + 1023 - (int)(w & 0x3FFu);
        p = min(p, P_ - 1);  // defensive; unreachable via tie-break
        float4 pr = ((const float4*)priors)[p];
        float hx = pr.z * 0.5f, hy = pr.w * 0.5f;
        float qx1 = pr.x - hx, qy1 = pr.y - hy, qx2 = pr.x + hx, qy2 = pr.y + hy;
        float pae = (qx2 - qx1) * (qy2 - qy1);
        float4 gb = sbox[tid];
        float ix1 = fmaxf(gb.x, qx1), iy1 = fmaxf(gb.y, qy1);
        float ix2 = fminf(gb.z, qx2), iy2 = fminf(gb.w, qy2);
        float iw = fmaxf(ix2 - ix1, 0.0f), ih = fmaxf(iy2 - iy1, 0.0f);
        float inter = iw * ih;
        // exact (bit-stable across blocks) IoU-form key for cross-block comparison
        float v = inter * frcp(sga[tid] + pae - inter);
        // layout [b][g][chunk]: fix kernel reads each (b,g)'s 24 keys contiguously
        bkey[((size_t)b * G_ + tid) * NCH + blockIdx.x] =
            ((unsigned long long)__float_as_uint(v) << 32) |
            (unsigned long long)(0xFFFFFFFFu - (unsigned)p);
    }

    if (tid == 0) {
        pl[b * NCH + blockIdx.x] = rs[0] + rs[1] + rs[2] + rs[3];
        pn[b * NCH + blockIdx.x] = rn[0] + rn[1] + rn[2] + rn[3];
    }
}

// ---------------- K2: per-image bkey reduce + override corrections (64 blocks) --------------
__global__ __launch_bounds__(64) void fix_kernel(
    const float* __restrict__ pred_loc, const float* __restrict__ priors,
    const float* __restrict__ gt, const unsigned long long* __restrict__ bkey,
    const unsigned short* __restrict__ mrec,
    double* __restrict__ corrl, unsigned int* __restrict__ corrn) {
    const int b = blockIdx.x, g = threadIdx.x;
    __shared__ int sp[G_];
    int p = -1;
    if (g < G_) {
        const unsigned long long* row = bkey + ((size_t)b * G_ + g) * NCH;
        unsigned long long m = 0ull;
#pragma unroll
        for (int c = 0; c < NCH; c++) m = max(m, row[c]);
        p = (int)(0xFFFFFFFFu - (unsigned)(m & 0xFFFFFFFFull));
        sp[g] = p;
    }
    __syncthreads();

    double delta = 0.0;
    unsigned int dn = 0;
    if (g < G_) {
        // last-write-wins: g is alive iff no larger g' shares the same best prior
        bool alive = true;
        for (int d = g + 1; d < G_; d++)
            if (sp[d] == p) alive = false;
        if (alive) {
            unsigned int m = mrec[(size_t)b * PAD_P + p];
            int i1 = (int)(m & 63u), i2 = (int)((m >> 6) & 63u);
            bool pos0 = (m >> 12) & 1u;
            int ri = (g == i1) ? i2 : i1;   // override bi=g -> rep flips to i1 unless g==i1
            float4 pr = ((const float4*)priors)[p];
            float4 l  = ((const float4*)pred_loc)[(size_t)b * P_ + p];
            const float* qr = gt + ((size_t)b * G_ + ri) * 5;
            float4 gbr = make_float4(qr[0], qr[1], qr[2], qr[3]);
            float gar = (qr[2] - qr[0]) * (qr[3] - qr[1]);
            float cnew = loss_term(pr, l, gbr, gar);
            float cold = 0.0f;
            if (pos0) {
                const float* q2 = gt + ((size_t)b * G_ + i2) * 5;
                float4 gb2 = make_float4(q2[0], q2[1], q2[2], q2[3]);
                float ga2 = (q2[2] - q2[0]) * (q2[3] - q2[1]);
                cold = loss_term(pr, l, gb2, ga2);   // cancels match's default term
            } else {
                dn = 1;                               // prior newly positive
            }
            delta = (double)cnew - (double)cold;
        }
    }
    for (int off = 32; off; off >>= 1) {
        delta += __shfl_down(delta, off, 64);
        dn    += __shfl_down(dn, off, 64);
    }
    if (g == 0) { corrl[b] = delta; corrn[b] = dn; }
}

// ---------------- K3: final reduction --------------------------------------------------------
__global__ __launch_bounds__(256) void final_kernel(
    const float* __restrict__ pl, const unsigned int* __restrict__ pn,
    const double* __restrict__ corrl, const unsigned int* __restrict__ corrn,
    float* __restrict__ out) {
    const int tid = threadIdx.x;
    double acc = 0.0;
    unsigned int n = 0;
    for (int i = tid; i < NBLK; i += 256) { acc += (double)pl[i]; n += pn[i]; }
    if (tid < B_) { acc += corrl[tid]; n += corrn[tid]; }
    for (int off = 32; off; off >>= 1) {
        acc += __shfl_down(acc, off, 64);
        n   += __shfl_down(n, off, 64);
    }
    __shared__ double ds[4];
    __shared__ unsigned int dns[4];
    const int lane = tid & 63, wv = tid >> 6;
    if (lane == 0) { ds[wv] = acc; dns[wv] = n; }
    __syncthreads();
    if (tid == 0) {
        double s = ds[0] + ds[1] + ds[2] + ds[3];
        unsigned int nn = dns[0] + dns[1] + dns[2] + dns[3];
        out[0] = (float)(s / (double)nn);
    }
}

extern "C" void kernel_launch(void* const* d_in, const int* in_sizes, int n_in,
                              void* d_out, int out_size, void* d_ws, size_t ws_size,
                              hipStream_t stream) {
    const float* pred_loc = (const float*)d_in[0];  // [B,P,4]
    const float* priors   = (const float*)d_in[1];  // [P,4]
    const float* gt       = (const float*)d_in[2];  // [B,G,5]
    float* out = (float*)d_out;

    char* ws = (char*)d_ws;
    unsigned long long* bkey = (unsigned long long*)ws;                   // 589824 B
    unsigned short* mrec = (unsigned short*)(ws + 589824);                // 3145728 B
    float*        pl    = (float*)(ws + 3735552);                         // 6144 B
    unsigned int* pn    = (unsigned int*)(ws + 3741696);                  // 6144 B
    double*       corrl = (double*)(ws + 3747840);                        // 512 B
    unsigned int* corrn = (unsigned int*)(ws + 3748352);                  // 256 B

    dim3 g1(NCH, B_);
    match_kernel<<<g1, 256, 0, stream>>>(pred_loc, priors, gt, bkey, mrec, pl, pn);

    fix_kernel<<<B_, 64, 0, stream>>>(pred_loc, priors, gt, bkey, mrec, corrl, corrn);

    final_kernel<<<1, 256, 0, stream>>>(pl, pn, corrl, corrn, out);
}